// Round 12
// baseline (164.489 us; speedup 1.0000x reference)
//
#include <hip/hip_runtime.h>

#define BATCH 32
#define HH 1024
#define WW 1024
#define NPIX (HH * WW)
#define NEROS 10
#define TPS 64                // 16-row tiles per sample (tail kernel)
#define NTILES (BATCH * TPS)  // 2048 (tail grid)
#define NB0 (BATCH * 256)     // conv0: 8192 blocks = 128 row-groups x 2 halves
#define FRPS 1024             // flag ushorts per sample: chunk-mask per row

__device__ __forceinline__ float4 ld4f(const float* p) {
    return *reinterpret_cast<const float4*>(p);
}

// Flags: per row, 16-bit mask; bit c = 64-px chunk c has a nonzero. Unflagged
// chunks are exact zeros: never written, never read. Pre-zeroed each launch.

// ---------------- iteration 0: global_load_lds staged bound+conv ------------
// Block = 8-row x 512-px tile, 512 threads (8 waves), 40 KB LDS (3 blocks/CU).
// Stage raw pred rows [ry-1,ry+9) (LDS slots 0..9) and tgt rows (slots 10..19)
// via __builtin_amdgcn_global_load_lds (16B/lane, no VGPR round-trip): 5
// instructions per wave, ~40KB in flight per block, un-serializable by the
// register allocator. Wave w computes image row ry+w; bound=(p-t)^2 is
// recomputed from LDS at consume time (VALU is idle). Chunk-sparse stores;
// flags are owned byte stores.
__global__ __launch_bounds__(512, 6) void conv0_kernel(
    const float* __restrict__ pred, const float* __restrict__ tgt,
    float* __restrict__ out, unsigned short* __restrict__ Fout,
    unsigned* __restrict__ cntOut, unsigned* __restrict__ omin,
    unsigned* __restrict__ omax, double* __restrict__ osum) {
    int blk = blockIdx.x;
    blk = (blk & 7) * (NB0 >> 3) + (blk >> 3);  // XCD swizzle (8192%8==0)
    const int s = blk >> 8, rest = blk & 255;
    const int ty = rest >> 1, half = rest & 1;
    const int ry = ty << 3;          // first output row
    const int x0 = half << 9;        // tile px origin (0 or 512)
    const int tid = threadIdx.x, lane = tid & 63, w = tid >> 6;  // w: 0..7
    const size_t sbase = (size_t)s * NPIX;

    __shared__ float sb[20 * 512];  // 40 KB: slots 0..9 pred, 10..19 tgt
    __shared__ float smn[8], smx[8], ssm[8];
    __shared__ unsigned sfb[8];

    // ---- stage: 40 segments (20 LDS rows x 2), 5 per wave, direct to LDS ----
#pragma unroll
    for (int i = 0; i < 5; ++i) {
        const int sid = w * 5 + i;           // 0..39
        const int slot = sid >> 1, seg = sid & 1;
        const bool isP = slot < 10;
        const int y = ry - 1 + (isP ? slot : slot - 10);
        if (y >= 0 && y < HH) {  // wave-uniform condition
            const float* g = (isP ? pred : tgt) + sbase + (size_t)y * WW + x0 +
                             (seg << 8) + (lane << 2);
            __builtin_amdgcn_global_load_lds(
                (const __attribute__((address_space(1))) unsigned*)(const
                                                                    void*)g,
                (__attribute__((address_space(3))) unsigned*)(void*)&sb
                    [(slot << 9) + (seg << 8)],
                16, 0, 0);
        } else {
            *reinterpret_cast<float4*>(
                &sb[(slot << 9) + (seg << 8) + (lane << 2)]) =
                make_float4(0.f, 0.f, 0.f, 0.f);
        }
    }

    // tile-edge scalars for this wave's row (issued before the barrier)
    const int y = ry + w;
    float peL = 0.f, teL = 0.f, peR = 0.f, teR = 0.f;
    if (lane == 0 && x0 > 0) {
        const size_t g = sbase + (size_t)y * WW + x0 - 1;
        peL = pred[g];
        teL = tgt[g];
    }
    if (lane == 63 && x0 + 512 < WW) {
        const size_t g = sbase + (size_t)y * WW + x0 + 512;
        peR = pred[g];
        teR = tgt[g];
    }
    __syncthreads();

    // ---- compute: wave w -> image row y, 2 quads of 4 px per lane ----
    const int pu = w, pc = w + 1, pd = w + 2;
    const int tu = w + 10, tc = w + 11, td = w + 12;
    float lmin = 3.4e38f, lmax = 0.f, lsum = 0.f;
    unsigned mask8 = 0u;

#pragma unroll
    for (int q = 0; q < 2; ++q) {
        const int xw = (q << 8) + (lane << 2);
        const float4 PU = *(const float4*)&sb[(pu << 9) + xw];
        const float4 PC = *(const float4*)&sb[(pc << 9) + xw];
        const float4 PD = *(const float4*)&sb[(pd << 9) + xw];
        const float4 TU = *(const float4*)&sb[(tu << 9) + xw];
        const float4 TC = *(const float4*)&sb[(tc << 9) + xw];
        const float4 TD = *(const float4*)&sb[(td << 9) + xw];
        float bU[4], bC[4], bD[4];
        bU[0] = (PU.x - TU.x) * (PU.x - TU.x);
        bU[1] = (PU.y - TU.y) * (PU.y - TU.y);
        bU[2] = (PU.z - TU.z) * (PU.z - TU.z);
        bU[3] = (PU.w - TU.w) * (PU.w - TU.w);
        bC[0] = (PC.x - TC.x) * (PC.x - TC.x);
        bC[1] = (PC.y - TC.y) * (PC.y - TC.y);
        bC[2] = (PC.z - TC.z) * (PC.z - TC.z);
        bC[3] = (PC.w - TC.w) * (PC.w - TC.w);
        bD[0] = (PD.x - TD.x) * (PD.x - TD.x);
        bD[1] = (PD.y - TD.y) * (PD.y - TD.y);
        bD[2] = (PD.z - TD.z) * (PD.z - TD.z);
        bD[3] = (PD.w - TD.w) * (PD.w - TD.w);

        float lf = __shfl_up(bC[3], 1);
        if (lane == 0) {
            if (q == 1) {
                const float pp = sb[(pc << 9) + 255];
                const float tt = sb[(tc << 9) + 255];
                lf = (pp - tt) * (pp - tt);
            } else {
                const float d = peL - teL;
                lf = (x0 > 0) ? d * d : 0.f;
            }
        }
        float rt = __shfl_down(bC[0], 1);
        if (lane == 63) {
            if (q == 0) {
                const float pp = sb[(pc << 9) + 256];
                const float tt = sb[(tc << 9) + 256];
                rt = (pp - tt) * (pp - tt);
            } else {
                const float d = peR - teR;
                rt = (x0 + 512 < WW) ? d * d : 0.f;
            }
        }
        const float lv[4] = {lf, bC[0], bC[1], bC[2]};
        const float rv[4] = {bC[1], bC[2], bC[3], rt};

        float O[4];
        bool nz = false;
#pragma unroll
        for (int j = 0; j < 4; ++j) {
            const float conv =
                0.2f * (bU[j] + bD[j] + bC[j] + lv[j] + rv[j]);
            const float er = fmaxf(conv - 0.5f, 0.f);
            O[j] = er;
            lmin = fminf(lmin, er);
            lmax = fmaxf(lmax, er);
            lsum += er;
            nz = nz || (er > 0.f);
        }
        const unsigned long long bal = __ballot(nz);
        // chunk = 16 lanes = 64 px; store only chunks containing a nonzero
        if ((bal >> ((lane >> 4) << 4)) & 0xFFFFull)
            *reinterpret_cast<float4*>(out + sbase + (size_t)y * WW + x0 +
                                       xw) =
                make_float4(O[0], O[1], O[2], O[3]);
        unsigned nib = 0u;
        if (bal & 0xFFFFull) nib |= 1u;
        if ((bal >> 16) & 0xFFFFull) nib |= 2u;
        if ((bal >> 32) & 0xFFFFull) nib |= 4u;
        if ((bal >> 48) & 0xFFFFull) nib |= 8u;
        mask8 |= nib << (q << 2);
    }
    // owned byte store: chunks [half*8, half*8+8) of row y
    if (lane == 0)
        ((unsigned char*)Fout)[(((unsigned)(s << 10) + y) << 1) + half] =
            (unsigned char)mask8;

    // ---- block reduce (8 waves) ----
#pragma unroll
    for (int off = 32; off > 0; off >>= 1) {
        lmin = fminf(lmin, __shfl_down(lmin, off));
        lmax = fmaxf(lmax, __shfl_down(lmax, off));
        lsum += __shfl_down(lsum, off);
    }
    if (lane == 0) {
        smn[w] = lmin;
        smx[w] = lmax;
        ssm[w] = lsum;
        sfb[w] = mask8;
    }
    __syncthreads();
    if (tid == 0) {
        unsigned any = sfb[0];
        float bmn = smn[0], bmx = smx[0], bsm = ssm[0];
#pragma unroll
        for (int i = 1; i < 8; ++i) {
            bmn = fminf(bmn, smn[i]);
            bmx = fmaxf(bmx, smx[i]);
            bsm += ssm[i];
            any |= sfb[i];
        }
        if (any) atomicAdd(cntOut, 1u);
        atomicMin(&omin[s], __float_as_uint(bmn));
        if (bmx > 0.f) atomicMax(&omax[s], __float_as_uint(bmx));
        if (bsm > 0.f) atomicAdd(&osum[s], (double)bsm);
    }
}

// ---------------- iterations 1..9 (chunk-sparse tail, R10 verbatim) ---------
__global__ __launch_bounds__(256, 4) void convt_kernel(
    const float* __restrict__ in, float* __restrict__ out,
    const unsigned short* __restrict__ Fprev, unsigned short* __restrict__ Fout,
    const unsigned* __restrict__ cntPrev, unsigned* __restrict__ cntOut,
    const unsigned* __restrict__ pmin, const unsigned* __restrict__ pmax,
    unsigned* __restrict__ omin, unsigned* __restrict__ omax,
    double* __restrict__ osum) {
    if (*cntPrev == 0u) return;  // field died: absorbing state

    int blk = blockIdx.x;
    blk = (blk & 7) * (NTILES >> 3) + (blk >> 3);
    const int s = blk >> 6, ty = blk & 63, ry = ty << 4;
    const int tid = threadIdx.x, lane = tid & 63, w = tid >> 6;
    const int xb = lane << 4;
    const size_t sbase = (size_t)s * NPIX;

    __shared__ unsigned short sM[18];  // masks of rows ry-1 .. ry+16
    __shared__ int sSkip;
    if (tid < 18) {
        const int yy = ry - 1 + tid;
        sM[tid] =
            (yy >= 0 && yy < HH) ? Fprev[s * FRPS + yy] : (unsigned short)0;
    }
    __syncthreads();
    if (tid == 0) {
        unsigned any = 0;
#pragma unroll
        for (int i = 0; i < 18; ++i) any |= sM[i];
        sSkip = (any == 0u);
    }
    __syncthreads();
    if (sSkip) {  // nothing in reach: tile output exactly zero
        if (tid == 0) atomicMin(&omin[s], 0u);
        return;
    }

    float a = 1.f, cc = 0.f;
    {
        const float mn = __uint_as_float(pmin[s]);
        const float mx = __uint_as_float(pmax[s]);
        const float ptp = mx - mn;
        if (ptp > 0.f) { a = 1.f / ptp; cc = mn; }
    }

    const int r0 = w << 2;
    float A[16], B[16], C[16], O[16];

    auto loadRow = [&](int y, float* V) {
        const unsigned mask = sM[y - ry + 1];
        if (!((mask >> (lane >> 2)) & 1u)) {
#pragma unroll
            for (int j = 0; j < 16; ++j) V[j] = 0.f;
            return;
        }
        const size_t idx = sbase + (size_t)y * WW + xb;
#pragma unroll
        for (int q = 0; q < 4; ++q) {
            const float4 v = ld4f(in + idx + 4 * q);
            V[4 * q + 0] = v.x;
            V[4 * q + 1] = v.y;
            V[4 * q + 2] = v.z;
            V[4 * q + 3] = v.w;
        }
    };

    loadRow(ry + r0 - 1, A);
    loadRow(ry + r0, B);

    float lmin = 3.4e38f, lmax = 0.f, lsum = 0.f;
    unsigned blockAny = 0u;

#pragma unroll
    for (int r = 0; r < 4; ++r) {
        const int y = ry + r0 + r;
        loadRow(y + 1, C);
        const int mi = r0 + r + 1;  // sM index of row y
        const bool act = (sM[mi - 1] | sM[mi] | sM[mi + 1]) != 0;
        if (act) {
            float lfe = __shfl_up(B[15], 1);
            if (lane == 0) lfe = 0.f;
            float rte = __shfl_down(B[0], 1);
            if (lane == 63) rte = 0.f;
            const float vert =
                1.f + (y > 0 ? 1.f : 0.f) + (y < HH - 1 ? 1.f : 0.f);
            bool nz = false;
#pragma unroll
            for (int j = 0; j < 16; ++j) {
                const float lf = (j == 0) ? lfe : B[j - 1];
                const float rt = (j == 15) ? rte : B[j + 1];
                const float conv = 0.2f * (A[j] + C[j] + B[j] + lf + rt);
                const int x = xb + j;
                const float kf = 0.2f * (vert + (x > 0 ? 1.f : 0.f) +
                                         (x < WW - 1 ? 1.f : 0.f));
                const float dil = (conv - cc * kf) * a;
                const float er = fmaxf(dil - 0.5f, 0.f);
                O[j] = er;
                lmin = fminf(lmin, er);
                lmax = fmaxf(lmax, er);
                lsum += er;
                nz = nz || (er > 0.f);
            }
            const unsigned long long bal = __ballot(nz);
            // chunk = 4 lanes = 64 px; store lane's 16 px iff chunk nonzero
            if (((bal >> ((lane >> 2) << 2)) & 0xFull) != 0ull) {
                const size_t oidx = sbase + (size_t)y * WW + xb;
#pragma unroll
                for (int q = 0; q < 4; ++q)
                    *reinterpret_cast<float4*>(out + oidx + 4 * q) =
                        make_float4(O[4 * q], O[4 * q + 1], O[4 * q + 2],
                                    O[4 * q + 3]);
            }
            unsigned rm = 0;
#pragma unroll
            for (int c = 0; c < 16; ++c)
                if ((bal >> (c << 2)) & 0xFull) rm |= 1u << c;
            if (lane == 0) Fout[s * FRPS + y] = (unsigned short)rm;  // owned
            blockAny |= rm;
        } else {
            lmin = fminf(lmin, 0.f);  // row is exactly zero (mask pre-zeroed)
        }
#pragma unroll
        for (int j = 0; j < 16; ++j) {
            A[j] = B[j];
            B[j] = C[j];
        }
    }

#pragma unroll
    for (int off = 32; off > 0; off >>= 1) {
        lmin = fminf(lmin, __shfl_down(lmin, off));
        lmax = fmaxf(lmax, __shfl_down(lmax, off));
        lsum += __shfl_down(lsum, off);
    }
    __shared__ float smn[4], smx[4], ssm[4];
    __shared__ unsigned sfb[4];
    if (lane == 0) {
        smn[w] = lmin;
        smx[w] = lmax;
        ssm[w] = lsum;
        sfb[w] = blockAny;
    }
    __syncthreads();
    if (tid == 0) {
        const unsigned any = sfb[0] | sfb[1] | sfb[2] | sfb[3];
        float bmn = smn[0], bmx = smx[0], bsm = ssm[0];
#pragma unroll
        for (int i = 1; i < 4; ++i) {
            bmn = fminf(bmn, smn[i]);
            bmx = fmaxf(bmx, smx[i]);
            bsm += ssm[i];
        }
        if (any) atomicAdd(cntOut, 1u);
        atomicMin(&omin[s], __float_as_uint(bmn));
        if (bmx > 0.f) atomicMax(&omax[s], __float_as_uint(bmx));
        if (bsm > 0.f) atomicAdd(&osum[s], (double)bsm);
    }
}

__global__ void init_kernel(unsigned* __restrict__ minb,
                            unsigned* __restrict__ maxb,
                            double* __restrict__ sums,
                            unsigned* __restrict__ F16u,
                            unsigned* __restrict__ cnt) {
    const int i = blockIdx.x * blockDim.x + threadIdx.x;
    if (i < NEROS * BATCH) {
        minb[i] = 0x7f800000u;  // +inf
        maxb[i] = 0u;
        sums[i] = 0.0;
    }
    if (i < NEROS * BATCH * FRPS / 2) F16u[i] = 0u;  // ushort masks, as uints
    if (i < NEROS) cnt[i] = 0u;
}

__global__ void final_kernel(const unsigned* __restrict__ minb,
                             const unsigned* __restrict__ maxb,
                             const double* __restrict__ sums,
                             float* __restrict__ out) {
    const int s = threadIdx.x;
    double tot = 0.0;
    if (s < BATCH) {
        for (int k = 0; k < NEROS; ++k) {
            const float mn = __uint_as_float(minb[k * BATCH + s]);
            const float mx = __uint_as_float(maxb[k * BATCH + s]);
            const double sm = sums[k * BATCH + s];
            const float ptp = mx - mn;
            double v;
            if (ptp > 0.f)
                v = (sm - (double)NPIX * (double)mn) / (double)ptp;
            else
                v = sm;
            tot += (double)((k + 1) * (k + 1)) * v;
        }
    }
#pragma unroll
    for (int off = 32; off > 0; off >>= 1) tot += __shfl_down(tot, off);
    if (s == 0) out[0] = (float)(tot / ((double)BATCH * (double)NPIX));
}

extern "C" void kernel_launch(void* const* d_in, const int* in_sizes, int n_in,
                              void* d_out, int out_size, void* d_ws,
                              size_t ws_size, hipStream_t stream) {
    const float* pred = (const float*)d_in[0];
    const float* tgt = (const float*)d_in[1];
    float* out = (float*)d_out;

    float* buf0 = (float*)d_ws;
    float* buf1 = buf0 + (size_t)BATCH * NPIX;
    unsigned* minb = (unsigned*)(buf1 + (size_t)BATCH * NPIX);
    unsigned* maxb = minb + NEROS * BATCH;
    double* sums = (double*)(maxb + NEROS * BATCH);
    unsigned short* F = (unsigned short*)(sums + NEROS * BATCH);
    unsigned* cnt = (unsigned*)(F + (size_t)NEROS * BATCH * FRPS);

    init_kernel<<<640, 256, 0, stream>>>(minb, maxb, sums, (unsigned*)F, cnt);

    conv0_kernel<<<NB0, 512, 0, stream>>>(pred, tgt, buf0, F, &cnt[0], minb,
                                          maxb, sums);

    float* bufs[2] = {buf0, buf1};
    for (int k = 1; k < NEROS; ++k) {
        const float* src = bufs[(k - 1) & 1];
        float* dst = bufs[k & 1];
        convt_kernel<<<NTILES, 256, 0, stream>>>(
            src, dst, F + (size_t)(k - 1) * BATCH * FRPS,
            F + (size_t)k * BATCH * FRPS, &cnt[k - 1], &cnt[k],
            minb + (size_t)(k - 1) * BATCH, maxb + (size_t)(k - 1) * BATCH,
            minb + (size_t)k * BATCH, maxb + (size_t)k * BATCH,
            sums + (size_t)k * BATCH);
    }

    final_kernel<<<1, 64, 0, stream>>>(minb, maxb, sums, out);
}

// Round 13
// 125.551 us; speedup vs baseline: 1.3101x; 1.3101x over previous
//
#include <hip/hip_runtime.h>

#define BATCH 32
#define HH 1024
#define WW 1024
#define NPIX (HH * WW)
#define NEROS 10
#define TPS 64                // 16-row tiles per sample (tail kernel)
#define NTILES (BATCH * TPS)  // 2048 (tail grid)
#define NB0 (BATCH * 128)     // conv0: 4096 8-row tiles
#define FRPS 1024             // flag words per sample: ushort chunk-mask per row

__device__ __forceinline__ float4 ld4f(const float* p) {
    return *reinterpret_cast<const float4*>(p);
}

// Flags: per row, a 16-bit mask; bit c set = 64-px chunk c of that row has a
// nonzero. Unflagged chunks are exact zeros and their memory is NEVER read or
// written. Every row's mask is STORED every iteration (owned stores, zero for
// empty rows), so no pre-zeroing of flag memory is needed.

// ---------------- iteration 0: LDS-staged bound+conv, chunk-sparse writes ----
// Block = 8-row tile, 512 threads (8 waves), 40 KB LDS (4 blocks/CU). Stage
// rows [ry-1, ry+9) of bound=(pred-tgt)^2 via flat coalesced bursts, then
// wave w computes image row ry+w from LDS. Stores happen per 64-px chunk
// (16-lane group) only where that chunk holds a nonzero.
__global__ __launch_bounds__(512, 8) void conv0_kernel(
    const float* __restrict__ pred, const float* __restrict__ tgt,
    float* __restrict__ out, unsigned short* __restrict__ Fout,
    unsigned* __restrict__ cntOut, unsigned* __restrict__ omin,
    unsigned* __restrict__ omax, double* __restrict__ osum) {
    int blk = blockIdx.x;
    blk = (blk & 7) * (NB0 >> 3) + (blk >> 3);  // XCD swizzle (4096%8==0)
    const int s = blk >> 7, ty = blk & 127, ry = ty << 3;
    const int tid = threadIdx.x, lane = tid & 63, w = tid >> 6;  // w: 0..7
    const size_t sbase = (size_t)s * NPIX;

    __shared__ float sb[10 * 1024];  // 40 KB

    // ---- stage: 10 rows x 1024 px = 2560 float4 slots, 5 per thread ----
    float4 pv[5], tv[5];
#pragma unroll
    for (int i = 0; i < 5; ++i) {
        const int slot = tid + 512 * i;
        const int y = ry - 1 + (slot >> 8);
        if (y >= 0 && y < HH) {
            const size_t idx = sbase + (size_t)y * WW + ((slot & 255) << 2);
            pv[i] = ld4f(pred + idx);
            tv[i] = ld4f(tgt + idx);
        } else {
            pv[i] = make_float4(0.f, 0.f, 0.f, 0.f);
            tv[i] = make_float4(0.f, 0.f, 0.f, 0.f);
        }
    }
#pragma unroll
    for (int i = 0; i < 5; ++i) {
        const int slot = tid + 512 * i;
        float4 b;
        b.x = (pv[i].x - tv[i].x) * (pv[i].x - tv[i].x);
        b.y = (pv[i].y - tv[i].y) * (pv[i].y - tv[i].y);
        b.z = (pv[i].z - tv[i].z) * (pv[i].z - tv[i].z);
        b.w = (pv[i].w - tv[i].w) * (pv[i].w - tv[i].w);
        *reinterpret_cast<float4*>(
            &sb[(slot >> 8) * 1024 + ((slot & 255) << 2)]) = b;
    }
    __syncthreads();

    // ---- compute: wave w handles image row y = ry+w ----
    float lmin = 3.4e38f, lmax = 0.f, lsum = 0.f;
    unsigned rowmask = 0u;
    const int y = ry + w;
#pragma unroll
    for (int q = 0; q < 4; ++q) {
        const int xw = (q << 8) + (lane << 2);
        const float4 U = *(const float4*)&sb[w * 1024 + xw];
        const float4 Cc = *(const float4*)&sb[(w + 1) * 1024 + xw];
        const float4 D = *(const float4*)&sb[(w + 2) * 1024 + xw];
        float lf = __shfl_up(Cc.w, 1);
        if (lane == 0) lf = (q > 0) ? sb[(w + 1) * 1024 + (q << 8) - 1] : 0.f;
        float rt = __shfl_down(Cc.x, 1);
        if (lane == 63)
            rt = (q < 3) ? sb[(w + 1) * 1024 + (q << 8) + 256] : 0.f;
        const float cv[4] = {Cc.x, Cc.y, Cc.z, Cc.w};
        const float uv[4] = {U.x, U.y, U.z, U.w};
        const float dv[4] = {D.x, D.y, D.z, D.w};
        const float lvv[4] = {lf, Cc.x, Cc.y, Cc.z};
        const float rvv[4] = {Cc.y, Cc.z, Cc.w, rt};
        float O[4];
        bool nz = false;
#pragma unroll
        for (int j = 0; j < 4; ++j) {
            const float conv = 0.2f * (uv[j] + dv[j] + cv[j] + lvv[j] + rvv[j]);
            const float er = fmaxf(conv - 0.5f, 0.f);
            O[j] = er;
            lmin = fminf(lmin, er);
            lmax = fmaxf(lmax, er);
            lsum += er;
            nz = nz || (er > 0.f);
        }
        const unsigned long long bal = __ballot(nz);
        // chunk = 16 lanes = 64 px; store only chunks containing a nonzero
        const bool myChunk =
            ((bal >> ((lane >> 4) << 4)) & 0xFFFFull) != 0ull;
        if (myChunk)
            *reinterpret_cast<float4*>(out + sbase + (size_t)y * WW + xw) =
                make_float4(O[0], O[1], O[2], O[3]);
        unsigned g = 0;
        if ((bal)&0xFFFFull) g |= 1u;
        if ((bal >> 16) & 0xFFFFull) g |= 2u;
        if ((bal >> 32) & 0xFFFFull) g |= 4u;
        if ((bal >> 48) & 0xFFFFull) g |= 8u;
        rowmask |= g << (q << 2);
    }
    if (lane == 0) Fout[s * FRPS + y] = (unsigned short)rowmask;  // owned row

    // ---- block reduce (8 waves) ----
#pragma unroll
    for (int off = 32; off > 0; off >>= 1) {
        lmin = fminf(lmin, __shfl_down(lmin, off));
        lmax = fmaxf(lmax, __shfl_down(lmax, off));
        lsum += __shfl_down(lsum, off);
    }
    __shared__ float smn[8], smx[8], ssm[8];
    __shared__ unsigned sfb[8];
    if (lane == 0) {
        smn[w] = lmin;
        smx[w] = lmax;
        ssm[w] = lsum;
        sfb[w] = rowmask;
    }
    __syncthreads();
    if (tid == 0) {
        unsigned any = sfb[0];
        float bmn = smn[0], bmx = smx[0], bsm = ssm[0];
#pragma unroll
        for (int i = 1; i < 8; ++i) {
            bmn = fminf(bmn, smn[i]);
            bmx = fmaxf(bmx, smx[i]);
            bsm += ssm[i];
            any |= sfb[i];
        }
        if (any) atomicAdd(cntOut, 1u);
        atomicMin(&omin[s], __float_as_uint(bmn));
        if (bmx > 0.f) atomicMax(&omax[s], __float_as_uint(bmx));
        if (bsm > 0.f) atomicAdd(&osum[s], (double)bsm);
    }
}

// ---------------- iterations 1..9 (chunk-sparse tail) ----------------
// Block = 16-row tile, 4 waves; wave w owns rows [ry+4w, ry+4w+4); lane owns
// 16 px (= quarter of a 64-px chunk; chunk = 4 lanes). Loads and stores are
// gated by the per-row chunk masks. Every row's mask is stored (0 when empty),
// so flag memory never needs pre-zeroing.
__global__ __launch_bounds__(256, 4) void convt_kernel(
    const float* __restrict__ in, float* __restrict__ out,
    const unsigned short* __restrict__ Fprev, unsigned short* __restrict__ Fout,
    const unsigned* __restrict__ cntPrev, unsigned* __restrict__ cntOut,
    const unsigned* __restrict__ pmin, const unsigned* __restrict__ pmax,
    unsigned* __restrict__ omin, unsigned* __restrict__ omax,
    double* __restrict__ osum) {
    if (*cntPrev == 0u) return;  // field died: absorbing state (F unread later)

    int blk = blockIdx.x;
    blk = (blk & 7) * (NTILES >> 3) + (blk >> 3);
    const int s = blk >> 6, ty = blk & 63, ry = ty << 4;
    const int tid = threadIdx.x, lane = tid & 63, w = tid >> 6;
    const int xb = lane << 4;
    const size_t sbase = (size_t)s * NPIX;

    __shared__ unsigned short sM[18];  // masks of rows ry-1 .. ry+16
    __shared__ int sSkip;
    if (tid < 18) {
        const int yy = ry - 1 + tid;
        sM[tid] =
            (yy >= 0 && yy < HH) ? Fprev[s * FRPS + yy] : (unsigned short)0;
    }
    __syncthreads();
    if (tid == 0) {
        unsigned any = 0;
#pragma unroll
        for (int i = 0; i < 18; ++i) any |= sM[i];
        sSkip = (any == 0u);
    }
    __syncthreads();
    if (sSkip) {  // nothing in reach: tile output exactly zero
        if (tid < 16) Fout[s * FRPS + ry + tid] = 0;  // owned zero masks
        if (tid == 0) atomicMin(&omin[s], 0u);
        return;
    }

    float a = 1.f, cc = 0.f;
    {
        const float mn = __uint_as_float(pmin[s]);
        const float mx = __uint_as_float(pmax[s]);
        const float ptp = mx - mn;
        if (ptp > 0.f) { a = 1.f / ptp; cc = mn; }
    }

    const int r0 = w << 2;
    float A[16], B[16], C[16], O[16];

    // load row y (mask-gated per chunk; sM==0 rows -> zeros, incl. borders)
    auto loadRow = [&](int y, float* V) {
        const unsigned mask = sM[y - ry + 1];
        if (!((mask >> (lane >> 2)) & 1u)) {
#pragma unroll
            for (int j = 0; j < 16; ++j) V[j] = 0.f;
            return;
        }
        const size_t idx = sbase + (size_t)y * WW + xb;
#pragma unroll
        for (int q = 0; q < 4; ++q) {
            const float4 v = ld4f(in + idx + 4 * q);
            V[4 * q + 0] = v.x;
            V[4 * q + 1] = v.y;
            V[4 * q + 2] = v.z;
            V[4 * q + 3] = v.w;
        }
    };

    loadRow(ry + r0 - 1, A);
    loadRow(ry + r0, B);

    float lmin = 3.4e38f, lmax = 0.f, lsum = 0.f;
    unsigned blockAny = 0u;

#pragma unroll
    for (int r = 0; r < 4; ++r) {
        const int y = ry + r0 + r;
        loadRow(y + 1, C);
        const int mi = r0 + r + 1;  // sM index of row y
        const bool act = (sM[mi - 1] | sM[mi] | sM[mi + 1]) != 0;
        if (act) {
            float lfe = __shfl_up(B[15], 1);
            if (lane == 0) lfe = 0.f;
            float rte = __shfl_down(B[0], 1);
            if (lane == 63) rte = 0.f;
            const float vert =
                1.f + (y > 0 ? 1.f : 0.f) + (y < HH - 1 ? 1.f : 0.f);
            bool nz = false;
#pragma unroll
            for (int j = 0; j < 16; ++j) {
                const float lf = (j == 0) ? lfe : B[j - 1];
                const float rt = (j == 15) ? rte : B[j + 1];
                const float conv = 0.2f * (A[j] + C[j] + B[j] + lf + rt);
                const int x = xb + j;
                const float kf = 0.2f * (vert + (x > 0 ? 1.f : 0.f) +
                                         (x < WW - 1 ? 1.f : 0.f));
                const float dil = (conv - cc * kf) * a;
                const float er = fmaxf(dil - 0.5f, 0.f);
                O[j] = er;
                lmin = fminf(lmin, er);
                lmax = fmaxf(lmax, er);
                lsum += er;
                nz = nz || (er > 0.f);
            }
            const unsigned long long bal = __ballot(nz);
            // chunk = 4 lanes = 64 px; store lane's 16 px iff chunk nonzero
            if (((bal >> ((lane >> 2) << 2)) & 0xFull) != 0ull) {
                const size_t oidx = sbase + (size_t)y * WW + xb;
#pragma unroll
                for (int q = 0; q < 4; ++q)
                    *reinterpret_cast<float4*>(out + oidx + 4 * q) =
                        make_float4(O[4 * q], O[4 * q + 1], O[4 * q + 2],
                                    O[4 * q + 3]);
            }
            unsigned rm = 0;
#pragma unroll
            for (int c = 0; c < 16; ++c)
                if ((bal >> (c << 2)) & 0xFull) rm |= 1u << c;
            if (lane == 0) Fout[s * FRPS + y] = (unsigned short)rm;  // owned
            blockAny |= rm;
        } else {
            if (lane == 0) Fout[s * FRPS + y] = 0;  // owned zero mask
            lmin = fminf(lmin, 0.f);  // row is exactly zero
        }
#pragma unroll
        for (int j = 0; j < 16; ++j) {
            A[j] = B[j];
            B[j] = C[j];
        }
    }

#pragma unroll
    for (int off = 32; off > 0; off >>= 1) {
        lmin = fminf(lmin, __shfl_down(lmin, off));
        lmax = fmaxf(lmax, __shfl_down(lmax, off));
        lsum += __shfl_down(lsum, off);
    }
    __shared__ float smn[4], smx[4], ssm[4];
    __shared__ unsigned sfb[4];
    if (lane == 0) {
        smn[w] = lmin;
        smx[w] = lmax;
        ssm[w] = lsum;
        sfb[w] = blockAny;
    }
    __syncthreads();
    if (tid == 0) {
        const unsigned any = sfb[0] | sfb[1] | sfb[2] | sfb[3];
        float bmn = smn[0], bmx = smx[0], bsm = ssm[0];
#pragma unroll
        for (int i = 1; i < 4; ++i) {
            bmn = fminf(bmn, smn[i]);
            bmx = fmaxf(bmx, smx[i]);
            bsm += ssm[i];
        }
        if (any) atomicAdd(cntOut, 1u);
        atomicMin(&omin[s], __float_as_uint(bmn));
        if (bmx > 0.f) atomicMax(&omax[s], __float_as_uint(bmx));
        if (bsm > 0.f) atomicAdd(&osum[s], (double)bsm);
    }
}

__global__ void init_kernel(unsigned* __restrict__ minb,
                            unsigned* __restrict__ maxb,
                            double* __restrict__ sums,
                            unsigned* __restrict__ cnt) {
    const int i = blockIdx.x * blockDim.x + threadIdx.x;
    if (i < NEROS * BATCH) {
        minb[i] = 0x7f800000u;  // +inf
        maxb[i] = 0u;
        sums[i] = 0.0;
    }
    if (i < NEROS) cnt[i] = 0u;
}

__global__ void final_kernel(const unsigned* __restrict__ minb,
                             const unsigned* __restrict__ maxb,
                             const double* __restrict__ sums,
                             float* __restrict__ out) {
    const int s = threadIdx.x;
    double tot = 0.0;
    if (s < BATCH) {
        for (int k = 0; k < NEROS; ++k) {
            const float mn = __uint_as_float(minb[k * BATCH + s]);
            const float mx = __uint_as_float(maxb[k * BATCH + s]);
            const double sm = sums[k * BATCH + s];
            const float ptp = mx - mn;
            double v;
            if (ptp > 0.f)
                v = (sm - (double)NPIX * (double)mn) / (double)ptp;
            else
                v = sm;
            tot += (double)((k + 1) * (k + 1)) * v;
        }
    }
#pragma unroll
    for (int off = 32; off > 0; off >>= 1) tot += __shfl_down(tot, off);
    if (s == 0) out[0] = (float)(tot / ((double)BATCH * (double)NPIX));
}

extern "C" void kernel_launch(void* const* d_in, const int* in_sizes, int n_in,
                              void* d_out, int out_size, void* d_ws,
                              size_t ws_size, hipStream_t stream) {
    const float* pred = (const float*)d_in[0];
    const float* tgt = (const float*)d_in[1];
    float* out = (float*)d_out;

    float* buf0 = (float*)d_ws;
    float* buf1 = buf0 + (size_t)BATCH * NPIX;
    unsigned* minb = (unsigned*)(buf1 + (size_t)BATCH * NPIX);
    unsigned* maxb = minb + NEROS * BATCH;
    double* sums = (double*)(maxb + NEROS * BATCH);
    unsigned short* F = (unsigned short*)(sums + NEROS * BATCH);
    unsigned* cnt = (unsigned*)(F + (size_t)NEROS * BATCH * FRPS);

    init_kernel<<<2, 256, 0, stream>>>(minb, maxb, sums, cnt);

    conv0_kernel<<<NB0, 512, 0, stream>>>(pred, tgt, buf0, F, &cnt[0], minb,
                                          maxb, sums);

    float* bufs[2] = {buf0, buf1};
    for (int k = 1; k < NEROS; ++k) {
        const float* src = bufs[(k - 1) & 1];
        float* dst = bufs[k & 1];
        convt_kernel<<<NTILES, 256, 0, stream>>>(
            src, dst, F + (size_t)(k - 1) * BATCH * FRPS,
            F + (size_t)k * BATCH * FRPS, &cnt[k - 1], &cnt[k],
            minb + (size_t)(k - 1) * BATCH, maxb + (size_t)(k - 1) * BATCH,
            minb + (size_t)k * BATCH, maxb + (size_t)k * BATCH,
            sums + (size_t)k * BATCH);
    }

    final_kernel<<<1, 64, 0, stream>>>(minb, maxb, sums, out);
}